// Round 1
// baseline (756.077 us; speedup 1.0000x reference)
//
#include <hip/hip_runtime.h>
#include <hip/hip_bf16.h>

// Problem constants (fixed by the reference)
#define B   8
#define D   512
#define N   512
#define L   512
#define DV  64
#define NL  (N * L)   // 262144

// ---------------------------------------------------------------------------
// Kernel 1: att[b,n,l] = sum_d k[b,d,n] * q[b,d,l]   (fp32, 64x64 tile, BK=16)
// grid (L/64, N/64, B), block 256
// ---------------------------------------------------------------------------
__global__ __launch_bounds__(256) void att_gemm(const float* __restrict__ k,
                                                const float* __restrict__ q,
                                                float* __restrict__ att) {
    const int b  = blockIdx.z;
    const int n0 = blockIdx.y * 64;
    const int l0 = blockIdx.x * 64;

    __shared__ float As[16][64];  // [dd][nn]
    __shared__ float Bs[16][64];  // [dd][ll]

    const float* kb = k + (size_t)b * D * N;
    const float* qb = q + (size_t)b * D * L;

    const int tid = threadIdx.x;
    const int lr = tid >> 4;            // 0..15 (d row within tile)
    const int lc = (tid & 15) << 2;     // 0..60 (col, float4)
    const int tx = tid & 15;            // l sub-tile
    const int ty = tid >> 4;            // n sub-tile

    float acc[4][4] = {};

    for (int d0 = 0; d0 < D; d0 += 16) {
        __syncthreads();
        *(float4*)&As[lr][lc] = *(const float4*)&kb[(size_t)(d0 + lr) * N + n0 + lc];
        *(float4*)&Bs[lr][lc] = *(const float4*)&qb[(size_t)(d0 + lr) * L + l0 + lc];
        __syncthreads();

#pragma unroll
        for (int kk = 0; kk < 16; ++kk) {
            float a[4], bb[4];
            *(float4*)a  = *(const float4*)&As[kk][ty << 2];
            *(float4*)bb = *(const float4*)&Bs[kk][tx << 2];
#pragma unroll
            for (int i = 0; i < 4; ++i)
#pragma unroll
                for (int j = 0; j < 4; ++j)
                    acc[i][j] = fmaf(a[i], bb[j], acc[i][j]);
        }
    }

#pragma unroll
    for (int i = 0; i < 4; ++i) {
        const int n = n0 + (ty << 2) + i;
        *(float4*)&att[((size_t)b * N + n) * L + l0 + (tx << 2)] = *(float4*)acc[i];
    }
}

// ---------------------------------------------------------------------------
// Kernel 2a: per-batch partial max. grid (64, B), block 256; each block 4096.
// ---------------------------------------------------------------------------
__global__ __launch_bounds__(256) void max_partial(const float* __restrict__ att,
                                                   float* __restrict__ partmax) {
    const int b   = blockIdx.y;
    const int blk = blockIdx.x;
    const float* base = att + (size_t)b * NL + (size_t)blk * 4096;
    const int tid = threadIdx.x;

    float m = -3.4e38f;
#pragma unroll
    for (int j = 0; j < 4; ++j) {
        float4 a = *(const float4*)&base[(size_t)j * 1024 + tid * 4];
        m = fmaxf(m, fmaxf(fmaxf(a.x, a.y), fmaxf(a.z, a.w)));
    }
#pragma unroll
    for (int off = 32; off >= 1; off >>= 1)
        m = fmaxf(m, __shfl_down(m, off));

    __shared__ float sm[4];
    const int wave = tid >> 6, lane = tid & 63;
    if (lane == 0) sm[wave] = m;
    __syncthreads();
    if (tid == 0)
        partmax[b * 64 + blk] = fmaxf(fmaxf(sm[0], sm[1]), fmaxf(sm[2], sm[3]));
}

// Kernel 2b: final max. grid B, block 64.
__global__ __launch_bounds__(64) void max_final(const float* __restrict__ partmax,
                                                float* __restrict__ maxb) {
    const int b = blockIdx.x;
    float m = partmax[b * 64 + threadIdx.x];
#pragma unroll
    for (int off = 32; off >= 1; off >>= 1)
        m = fmaxf(m, __shfl_down(m, off));
    if (threadIdx.x == 0) maxb[b] = m;
}

// ---------------------------------------------------------------------------
// Kernel 3: p = exp(att - max); denom += sum(p); numer[b,dv] += dot(p, v[b,dv,:])
// grid (NL/1024, B), block 256. Each block owns a 1024-wide chunk.
// ---------------------------------------------------------------------------
__global__ __launch_bounds__(256) void softmax_pv(const float* __restrict__ att,
                                                  const float* __restrict__ v,
                                                  const float* __restrict__ maxb,
                                                  float* __restrict__ numer,
                                                  float* __restrict__ denom) {
    const int b     = blockIdx.y;
    const int chunk = blockIdx.x;
    const size_t base = (size_t)b * NL + (size_t)chunk * 1024;
    const int tid  = threadIdx.x;
    const int wave = tid >> 6, lane = tid & 63;

    const float mb = maxb[b];
    float4 a4 = *(const float4*)&att[base + tid * 4];
    const float p0 = __expf(a4.x - mb);
    const float p1 = __expf(a4.y - mb);
    const float p2 = __expf(a4.z - mb);
    const float p3 = __expf(a4.w - mb);

    // denominator partial
    {
        float s = (p0 + p1) + (p2 + p3);
#pragma unroll
        for (int off = 32; off >= 1; off >>= 1)
            s += __shfl_down(s, off);
        __shared__ float sd[4];
        if (lane == 0) sd[wave] = s;
        __syncthreads();
        if (tid == 0)
            atomicAdd(&denom[b], (sd[0] + sd[1]) + (sd[2] + sd[3]));
    }

    // numerator: for each dv, dot(p_chunk, v_chunk)
    __shared__ float part[DV * 4];
    const float* vb = v + (size_t)b * DV * (size_t)NL + (size_t)chunk * 1024;

    for (int dv = 0; dv < DV; ++dv) {
        float4 v4 = *(const float4*)&vb[(size_t)dv * NL + tid * 4];
        float acc = fmaf(p0, v4.x, fmaf(p1, v4.y, fmaf(p2, v4.z, p3 * v4.w)));
#pragma unroll
        for (int off = 32; off >= 1; off >>= 1)
            acc += __shfl_down(acc, off);
        if (lane == 0) part[dv * 4 + wave] = acc;
    }
    __syncthreads();
    if (tid < DV) {
        float s = (part[tid * 4] + part[tid * 4 + 1]) +
                  (part[tid * 4 + 2] + part[tid * 4 + 3]);
        atomicAdd(&numer[b * DV + tid], s);
    }
}

// Kernel 4: out = numer / denom
__global__ __launch_bounds__(512) void finalize(const float* __restrict__ numer,
                                                const float* __restrict__ denom,
                                                float* __restrict__ out) {
    const int i = threadIdx.x;
    out[i] = numer[i] / denom[i >> 6];
}

extern "C" void kernel_launch(void* const* d_in, const int* in_sizes, int n_in,
                              void* d_out, int out_size, void* d_ws, size_t ws_size,
                              hipStream_t stream) {
    const float* k = (const float*)d_in[0];
    const float* q = (const float*)d_in[1];
    const float* v = (const float*)d_in[2];
    float* out = (float*)d_out;

    float* att     = (float*)d_ws;                  // B*NL floats = 8 MB
    float* partmax = att + (size_t)B * NL;          // B*64
    float* maxb    = partmax + B * 64;              // B
    float* numer   = maxb + B;                      // B*DV
    float* denom   = numer + B * DV;                // B

    // zero numer+denom (contiguous)
    hipMemsetAsync(numer, 0, (B * DV + B) * sizeof(float), stream);

    att_gemm  <<<dim3(L / 64, N / 64, B), 256, 0, stream>>>(k, q, att);
    max_partial<<<dim3(64, B), 256, 0, stream>>>(att, partmax);
    max_final <<<B, 64, 0, stream>>>(partmax, maxb);
    softmax_pv<<<dim3(NL / 1024, B), 256, 0, stream>>>(att, v, maxb, numer, denom);
    finalize  <<<1, B * DV, 0, stream>>>(numer, denom, out);
}